// Round 8
// baseline (178.179 us; speedup 1.0000x reference)
//
#include <hip/hip_runtime.h>
#include <hip/hip_fp16.h>
#include <stdint.h>

#define NPTS (96*96*96)          // 884736
#define NP5  (NPTS*5)            // 4423680 entries (point,vertex)

// Dense lattice grid (interval arithmetic from fixed domain: z,y,x in [0,95],
// image in [0,1); incl. rank-adjust, r-offset, blur padding, +/-2 margin):
//   q0 in [-3,25], q1 in [-14,14], q2 in [-16,8], q3 in [-17,3]
#define GD1 33
#define GD2 29
#define GD3 25
#define GO0 5
#define GO1 16
#define GO2 18
#define GO3 19
#define GS3 5
#define GS2 (GD3*GS3)      // 125
#define GS1 (GD2*GS2)      // 3625
#define GS0 (GD1*GS1)      // 119625
#define GCELLS (31*GS0)    // 3708375
#define GCELLS1 (GCELLS+1) // + trash cell for (never-expected) OOB
#define GSSUM (GS0+GS1+GS2+GS3)  // 123380

#define LHS 2048           // block-local LDS hash slots (1280 entries -> load <=0.625)

struct LatPt { int cell[5]; float w[5]; };
struct F5 { float s0, s1, s2, s3, w; };

// Per-cell value record: 12B = { q01:half2, q23:half2, w4:float }.
// OCCUPANCY-GATED reads everywhere (bitmap): unoccupied cells are NEVER
// trusted (vals holds garbage there); no pass zero-fills them.

// Shared per-point lattice math macro producing rank[5], rem0i[4], b[]
#define LATTICE_MATH(n)                                                        \
  int x = n % 96, y = (n / 96) % 96, z = n / (96 * 96);                        \
  float cf[4];                                                                 \
  cf[0] = ((float)z / 5.0f) * 2.8867513459481287f;                             \
  cf[1] = ((float)y / 5.0f) * 1.6666666666666667f;                             \
  cf[2] = ((float)x / 5.0f) * 1.1785113019775793f;                             \
  cf[3] = (imgv / 0.25f) * 0.9128709291752769f;                                \
  float elev[5];                                                               \
  float sm = 0.f;                                                              \
  _Pragma("unroll")                                                            \
  for (int i = 4; i >= 1; --i){ float c = cf[i-1]; elev[i] = sm - (float)i * c; sm += c; } \
  elev[0] = sm;                                                                \
  float rem0[5]; float sumrd_f = 0.f;                                          \
  _Pragma("unroll")                                                            \
  for (int i = 0; i < 5; i++){ float rd = rintf(elev[i] / 5.0f); rem0[i] = rd * 5.0f; sumrd_f += rd; } \
  int sum_rd = (int)sumrd_f;                                                   \
  float diff[5];                                                               \
  _Pragma("unroll")                                                            \
  for (int i = 0; i < 5; i++) diff[i] = elev[i] - rem0[i];                     \
  int rank[5];                                                                 \
  _Pragma("unroll")                                                            \
  for (int i = 0; i < 5; i++){                                                 \
    int r = 0;                                                                 \
    _Pragma("unroll")                                                          \
    for (int j = 0; j < 5; j++){                                               \
      r += (diff[j] > diff[i] || (diff[j] == diff[i] && j < i)) ? 1 : 0;       \
    }                                                                          \
    rank[i] = r + sum_rd;                                                      \
  }                                                                            \
  _Pragma("unroll")                                                            \
  for (int i = 0; i < 5; i++){                                                 \
    if (rank[i] < 0)      { rank[i] += 5; rem0[i] += 5.0f; }                   \
    else if (rank[i] > 4) { rank[i] -= 5; rem0[i] -= 5.0f; }                   \
  }                                                                            \
  float b[6] = {0.f,0.f,0.f,0.f,0.f,0.f};                                      \
  _Pragma("unroll")                                                            \
  for (int i = 0; i < 5; i++){                                                 \
    float v = (elev[i] - rem0[i]) / 5.0f;                                      \
    b[4 - rank[i]] += v;                                                       \
    b[5 - rank[i]] -= v;                                                       \
  }                                                                            \
  b[0] += 1.0f + b[5];                                                         \
  int rem0i[4];                                                                \
  _Pragma("unroll")                                                            \
  for (int i = 0; i < 4; i++) rem0i[i] = (int)rem0[i];

// Dense-path per-point result (shared by build & slice — bit-identical math).
__device__ __forceinline__ LatPt lat_compute(int n, float imgv)
{
  LATTICE_MATH(n)
  LatPt p;
  #pragma unroll
  for (int r = 0; r < 5; r++){
    int q0 = (rem0i[0] / 5) - (rank[0] < 5 - r ? 0 : 1) + GO0;
    int q1 = (rem0i[1] / 5) - (rank[1] < 5 - r ? 0 : 1) + GO1;
    int q2 = (rem0i[2] / 5) - (rank[2] < 5 - r ? 0 : 1) + GO2;
    int q3 = (rem0i[3] / 5) - (rank[3] < 5 - r ? 0 : 1) + GO3;
    int cell = (((q0 * GD1 + q1) * GD2 + q2) * GD3 + q3) * 5 + r;
    if ((unsigned)cell >= (unsigned)GCELLS) cell = GCELLS;
    p.cell[r] = cell;
    p.w[r] = b[r];
  }
  return p;
}

// Phase 1: hybrid chain-build + LDS-walk aggregation (R0 structure verbatim —
// best-measured build variant: 49-51 us).
__global__ void k_build_hyb(const float* __restrict__ image,
                            const float* __restrict__ input_,
                            int* __restrict__ head,
                            int4* __restrict__ nodes)
{
  __shared__ int   ls_cell[LHS];
  __shared__ int   ls_head[LHS];
  __shared__ short ls_next[1280];
  __shared__ float ls_w[1280];
  __shared__ float ls_q[256 * 4];     // stride 4, 16B aligned -> ds_read_b128
  __shared__ short ls_slot[1280];     // dense list of occupied slots
  __shared__ int   ls_cnt;

  int tid = threadIdx.x;
  #pragma unroll
  for (int i = 0; i < LHS / 256; i++){
    ls_cell[tid + 256 * i] = -1;
    ls_head[tid + 256 * i] = -1;
  }
  if (tid == 0) ls_cnt = 0;
  __syncthreads();

  int n = blockIdx.x * 256 + tid;
  float q0 = input_[n], q1 = input_[NPTS + n], q2 = input_[2 * NPTS + n], q3 = input_[3 * NPTS + n];
  *reinterpret_cast<float4*>(&ls_q[tid * 4]) = make_float4(q0, q1, q2, q3);
  LatPt P = lat_compute(n, image[n]);

  #pragma unroll
  for (int r = 0; r < 5; r++){
    int cell = P.cell[r];
    unsigned int h = ((unsigned int)cell * 2654435761u) & (LHS - 1);
    while (true){
      int prev = atomicCAS(&ls_cell[h], -1, cell);
      if (prev == -1){
        int li = atomicAdd(&ls_cnt, 1);      // winner registers the slot
        ls_slot[li] = (short)h;
        break;
      }
      if (prev == cell) break;
      h = (h + 1) & (LHS - 1);
    }
    int e = tid * 5 + r;
    ls_w[e] = P.w[r];
    ls_next[e] = (short)atomicExch(&ls_head[h], e);   // local chain push
  }
  __syncthreads();

  int cnt = ls_cnt;
  int blockBase = blockIdx.x * 1280;
  for (int i = tid; i < cnt; i += 256){
    int slot = ls_slot[i];
    int cell = ls_cell[slot];
    float s0 = 0.f, s1 = 0.f, s2 = 0.f, s3 = 0.f, s4 = 0.f;
    int e = ls_head[slot];
    while (e >= 0){
      int en = ls_next[e];                 // next-hop pointer issues first
      float w = ls_w[e];
      float4 q = *reinterpret_cast<const float4*>(&ls_q[(e / 5) * 4]);  // b128
      s0 += w * q.x; s1 += w * q.y; s2 += w * q.z; s3 += w * q.w; s4 += w;
      e = en;
    }
    int node = blockBase + i;              // dense list position = node index
    int old = atomicExch(&head[cell], node);
    __half2 h01 = __floats2half2_rn(s0, s1);
    __half2 h23 = __floats2half2_rn(s2, s3);
    int4 raw;
    raw.x = old;
    raw.y = *reinterpret_cast<int*>(&h01);
    raw.z = *reinterpret_cast<int*>(&h23);
    raw.w = __float_as_int(s4);
    nodes[node] = raw;                     // single 16B store
  }
}

// Phase 2: gather — walk pre-summed node chains (one 16B load per hop);
// write the 12B cell record for OCCUPIED cells only; emit occupancy bitmap.
__global__ void k_gather_agg(const int* __restrict__ head,
                             const int4* __restrict__ nodes,
                             int3* __restrict__ vals,
                             unsigned int* __restrict__ bitmap)
{
  int c = blockIdx.x * blockDim.x + threadIdx.x;
  int e = -1;
  if (c < GCELLS1) e = head[c];
  bool occ = (e >= 0);
  unsigned long long mask = __ballot(occ);
  int lane = threadIdx.x & 63;
  if (lane == 0)       bitmap[c >> 5] = (unsigned int)(mask & 0xffffffffu);
  else if (lane == 32) bitmap[c >> 5] = (unsigned int)(mask >> 32);
  if (!occ) return;                      // unoccupied cells are never read

  float s0 = 0.f, s1 = 0.f, s2 = 0.f, s3 = 0.f, s4 = 0.f;
  while (e >= 0){
    int4 raw = nodes[e];                 // one 16B load: next+q01+q23+w4
    __half2 h01 = *reinterpret_cast<__half2*>(&raw.y);
    __half2 h23 = *reinterpret_cast<__half2*>(&raw.z);
    float2 f01 = __half22float2(h01);
    float2 f23 = __half22float2(h23);
    s0 += f01.x; s1 += f01.y; s2 += f23.x; s3 += f23.y;
    s4 += __int_as_float(raw.w);
    e = raw.x;
  }
  __half2 o01 = __floats2half2_rn(s0, s1);
  __half2 o23 = __floats2half2_rn(s2, s3);
  int3 rec;
  rec.x = *reinterpret_cast<int*>(&o01);
  rec.y = *reinterpret_cast<int*>(&o23);
  rec.z = __float_as_int(s4);
  vals[c] = rec;
}

// Gated decode: rec words zeroed unless occupied (cndmask; halves of 0 -> 0.0f).
__device__ __forceinline__ F5 decz(int3 rec, bool occ)
{
  if (!occ){ rec.x = 0; rec.y = 0; rec.z = 0; }
  float2 f01 = __half22float2(*reinterpret_cast<__half2*>(&rec.x));
  float2 f23 = __half22float2(*reinterpret_cast<__half2*>(&rec.y));
  F5 r; r.s0 = f01.x; r.s1 = f01.y; r.s2 = f23.x; r.s3 = f23.y;
  r.w = __int_as_float(rec.z);
  return r;
}

// Gated 3-point combine: 0.5*a + 0.25*(b+c), zeroed unless g (node occupancy).
// FLOP order identical to the old nested ublur/ublur2 code.
__device__ __forceinline__ F5 comb(const F5& a, const F5& b, const F5& c, bool g)
{
  F5 r;
  r.s0 = g ? 0.5f * a.s0 + 0.25f * (b.s0 + c.s0) : 0.f;
  r.s1 = g ? 0.5f * a.s1 + 0.25f * (b.s1 + c.s1) : 0.f;
  r.s2 = g ? 0.5f * a.s2 + 0.25f * (b.s2 + c.s2) : 0.f;
  r.s3 = g ? 0.5f * a.s3 + 0.25f * (b.s3 + c.s3) : 0.f;
  r.w  = g ? 0.5f * a.w  + 0.25f * (b.w  + c.w ) : 0.f;
  return r;
}

// BRANCHLESS two-level stencil at node (d0,r0): outer offsets O, inner I.
// All 9 leaf addresses computed up front; 9 bitmap + 9 record loads issue
// back-to-back (MLP ~18) with no divergent fences. OOB addresses (reads the
// old gated code never issued; values discarded by gating) are clamped to 0.
// Leaf 3j is node j itself (self-weight 0.5), so occ(node j) == oc[3j].
__device__ __forceinline__ F5 stencil9(const unsigned int* __restrict__ bitmap,
                                       const int3* __restrict__ vin,
                                       int d0, int r0,
                                       int dPaO, int dPbO, int dMaO, int dMbO,
                                       int dPaI, int dPbI, int dMaI, int dMbI)
{
  int bd[3], br[3];
  bd[0] = d0;                           br[0] = r0;
  bd[1] = d0 + (r0 == 4 ? dPbO : dPaO); br[1] = (r0 == 4) ? 0 : r0 + 1;
  bd[2] = d0 + (r0 == 0 ? dMbO : dMaO); br[2] = (r0 == 0) ? 4 : r0 - 1;
  int ld[9];
  #pragma unroll
  for (int j = 0; j < 3; j++){
    ld[3*j]   = bd[j];
    ld[3*j+1] = bd[j] + (br[j] == 4 ? dPbI : dPaI);
    ld[3*j+2] = bd[j] + (br[j] == 0 ? dMbI : dMaI);
  }
  bool ib[9]; unsigned wv[9];
  #pragma unroll
  for (int k = 0; k < 9; k++){
    ib[k] = (unsigned)ld[k] < (unsigned)GCELLS;
    if (!ib[k]) ld[k] = 0;
    wv[k] = bitmap[ld[k] >> 5];
  }
  int3 rv[9];
  #pragma unroll
  for (int k = 0; k < 9; k++) rv[k] = vin[ld[k]];
  bool oc[9];
  #pragma unroll
  for (int k = 0; k < 9; k++) oc[k] = ib[k] && ((wv[k] >> (ld[k] & 31)) & 1u);

  F5 B0 = comb(decz(rv[0], oc[0]), decz(rv[1], oc[1]), decz(rv[2], oc[2]), oc[0]);
  F5 B1 = comb(decz(rv[3], oc[3]), decz(rv[4], oc[4]), decz(rv[5], oc[5]), oc[3]);
  F5 B2 = comb(decz(rv[6], oc[6]), decz(rv[7], oc[7]), decz(rv[8], oc[8]), oc[6]);
  return comb(B0, B1, B2, oc[0]);
}

// Phase 3a: FUSED pair of blur directions: vout = blurB(blurA(vin)).
// One batched stencil9 (outer = B, inner = A). Occupied-only writes.
__global__ void k_blur2_d(const unsigned int* __restrict__ bitmap,
                          const int3* __restrict__ vin,
                          int3* __restrict__ vout,
                          int dPaA, int dPbA, int dMaA, int dMbA,
                          int dPaB, int dPbB, int dMaB, int dMbB)
{
  int c = blockIdx.x * blockDim.x + threadIdx.x;
  if (c >= GCELLS) return;
  if (!((bitmap[c >> 5] >> (c & 31)) & 1u)) return;
  int rc = c % 5;
  F5 o = stencil9(bitmap, vin, c, rc,
                  dPaB, dPbB, dMaB, dMbB,
                  dPaA, dPbA, dMaA, dMbA);
  __half2 o01 = __floats2half2_rn(o.s0, o.s1);
  __half2 o23 = __floats2half2_rn(o.s2, o.s3);
  int3 rec;
  rec.x = *reinterpret_cast<int*>(&o01);
  rec.y = *reinterpret_cast<int*>(&o23);
  rec.z = __float_as_int(o.w);
  vout[c] = rec;
}

// Phase 3b: FUSED TRIPLE: vout = blurC(blurB(blurA(vin))).
// 3 sequential stencil9 groups (C-children), each with 18 batched loads.
__global__ void k_blur3_d(const unsigned int* __restrict__ bitmap,
                          const int3* __restrict__ vin,
                          int3* __restrict__ vout,
                          int dPaA, int dPbA, int dMaA, int dMbA,
                          int dPaB, int dPbB, int dMaB, int dMbB,
                          int dPaC, int dPbC, int dMaC, int dMbC)
{
  int c = blockIdx.x * blockDim.x + threadIdx.x;
  if (c >= GCELLS) return;
  if (!((bitmap[c >> 5] >> (c & 31)) & 1u)) return;
  int rc = c % 5;
  int cd1 = c + (rc == 4 ? dPbC : dPaC); int cr1 = (rc == 4) ? 0 : rc + 1;
  int cd2 = c + (rc == 0 ? dMbC : dMaC); int cr2 = (rc == 0) ? 4 : rc - 1;

  F5 C0 = stencil9(bitmap, vin, c,   rc,  dPaB, dPbB, dMaB, dMbB, dPaA, dPbA, dMaA, dMbA);
  F5 C1 = stencil9(bitmap, vin, cd1, cr1, dPaB, dPbB, dMaB, dMbB, dPaA, dPbA, dMaA, dMbA);
  F5 C2 = stencil9(bitmap, vin, cd2, cr2, dPaB, dPbB, dMaB, dMbB, dPaA, dPbA, dMaA, dMbA);

  float o0 = 0.5f * C0.s0 + 0.25f * (C1.s0 + C2.s0);
  float o1 = 0.5f * C0.s1 + 0.25f * (C1.s1 + C2.s1);
  float o2 = 0.5f * C0.s2 + 0.25f * (C1.s2 + C2.s2);
  float o3 = 0.5f * C0.s3 + 0.25f * (C1.s3 + C2.s3);
  float ow = 0.5f * C0.w  + 0.25f * (C1.w  + C2.w);

  __half2 o01 = __floats2half2_rn(o0, o1);
  __half2 o23 = __floats2half2_rn(o2, o3);
  int3 rec;
  rec.x = *reinterpret_cast<int*>(&o01);
  rec.y = *reinterpret_cast<int*>(&o23);
  rec.z = __float_as_int(ow);
  vout[c] = rec;
}

// Phase 4: slice + normalize — recomputes cells & weights via lat_compute.
// Every sliced cell is occupied by construction (it received this point's
// splat), so no gating needed here.
__global__ void k_slice_d(const float* __restrict__ image,
                          const int3* __restrict__ vals,
                          float* __restrict__ out)
{
  int n = blockIdx.x * blockDim.x + threadIdx.x;
  if (n >= NPTS) return;
  LatPt P = lat_compute(n, image[n]);

  float s0 = 0.f, s1 = 0.f, s2 = 0.f, s3 = 0.f, s4 = 0.f;
  #pragma unroll
  for (int r = 0; r < 5; r++){
    float w = P.w[r];
    int3 rec = vals[P.cell[r]];
    float2 f01 = __half22float2(*reinterpret_cast<__half2*>(&rec.x));
    float2 f23 = __half22float2(*reinterpret_cast<__half2*>(&rec.y));
    s0 += w * f01.x; s1 += w * f01.y; s2 += w * f23.x; s3 += w * f23.y;
    s4 += w * __int_as_float(rec.z);
  }
  float denom = s4 + 2.2204460492503131e-16f;
  out[n]            = s0 / denom;
  out[NPTS + n]     = s1 / denom;
  out[2 * NPTS + n] = s2 / denom;
  out[3 * NPTS + n] = s3 / denom;
}

// ============================ HOST ============================

extern "C" void kernel_launch(void* const* d_in, const int* in_sizes, int n_in,
                              void* d_out, int out_size, void* d_ws, size_t ws_size,
                              hipStream_t stream)
{
  const float* input_ = (const float*)d_in[0];
  const float* image  = (const float*)d_in[1];
  float* out = (float*)d_out;
  char* ws = (char*)d_ws;

  const int NB = (NPTS + 255) / 256;
  const int CB = (GCELLS1 + 255) / 256;
  const size_t BMWORDS = (size_t)CB * 8;
  const int Sj[5] = { GS0, GS1, GS2, GS3, 0 };
  int dPa[5], dPb[5], dMa[5], dMb[5];
  for (int j = 0; j < 5; j++){
    dPa[j] = 1 - Sj[j];
    dPb[j] = GSSUM - Sj[j] - 4;
    dMa[j] = Sj[j] - 1;
    dMb[j] = Sj[j] - GSSUM + 4;
  }

  // Workspace (~131 MB aliased): bitmap | head | nodes | valsA.
  // valsB ALIASED over head+nodes (dead after k_gather_agg). Stale bytes in
  // unoccupied cells of either vals buffer are NEVER read (bitmap gating).
  size_t o = 0;
  size_t off_bm   = o; o += BMWORDS * 4;              o = (o + 255) & ~(size_t)255;
  size_t off_dead = o;                                 // head+nodes region
  size_t off_head = o; o += (size_t)GCELLS1 * 4;      o = (o + 255) & ~(size_t)255;
  size_t off_node = o; o += (size_t)NP5 * 16;         o = (o + 255) & ~(size_t)255;
  size_t dead_end = o;
  size_t off_vA   = o; o += (size_t)GCELLS1 * 12;
  size_t vB_need  = (size_t)GCELLS1 * 12;
  size_t off_vB   = off_dead;
  if (dead_end - off_dead < vB_need || o > ws_size){
    // non-aliased fallback layout
    off_vB = (o + 255) & ~(size_t)255;
  }

  unsigned int* bitmap = (unsigned int*)(ws + off_bm);
  int*          head   = (int*)(ws + off_head);
  int4*         nodes  = (int4*)(ws + off_node);
  int3*         valsA  = (int3*)(ws + off_vA);
  int3*         valsB  = (int3*)(ws + off_vB);

  hipMemsetAsync(head, 0xFF, (size_t)GCELLS1 * 4, stream);

  k_build_hyb<<<NB, 256, 0, stream>>>(image, input_, head, nodes);
  k_gather_agg<<<CB, 256, 0, stream>>>(head, nodes, valsA, bitmap);

  // Fused j=0+1: A -> B (occupied-only writes; gated, batched reads)
  k_blur2_d<<<CB, 256, 0, stream>>>(bitmap, valsA, valsB,
                                    dPa[0], dPb[0], dMa[0], dMb[0],
                                    dPa[1], dPb[1], dMa[1], dMb[1]);
  // Fused TRIPLE j=2+3+4: B -> A
  k_blur3_d<<<CB, 256, 0, stream>>>(bitmap, valsB, valsA,
                                    dPa[2], dPb[2], dMa[2], dMb[2],
                                    dPa[3], dPb[3], dMa[3], dMb[3],
                                    dPa[4], dPb[4], dMa[4], dMb[4]);

  k_slice_d<<<NB, 256, 0, stream>>>(image, valsA, out);
}